// Round 14
// baseline (169.139 us; speedup 1.0000x reference)
//
#include <hip/hip_runtime.h>
#include <math.h>

// Kalman filter. Covariance trajectory is batch-independent AND (for F==I)
// P never materialized:
//   G = S^{-1} HP (GJ on [S|HP]); K = G^T; HP_next = R*G + HQ (HQ = H*Q const)
// HP-form is self-correcting -> fp32 throughout.
//   Kernel 1 (traj): fId path runs ENTIRELY in wave 0 (no __syncthreads in
//     the loop): Phase S computed by the same wave (hoisted H-row regs),
//     register GJ with readlane broadcasts, posted K stores, convergence
//     break via ballot, register-sourced tail fill. Publishes tailStart.
//   Kernel 2 (batch): one wave per batch, LDS-FREE: x/innov/z are
//     wave-uniform per lane index -> all broadcasts via v_readlane feeding
//     v_fma. Phase A: x' = x + K(z-Hx). Phase B (t>=tailStart): constant-K
//     M_c = I - K_c H rows built once in regs, x' = M_c x + K_c z.

#define S_DIM 32
#define O_DIM 16
#define K_STRIDE 512   // floats per step in ws: K (32x16 row-major)
#define HS 36          // padded fp32 stride (144B rows, 16B-aligned)

__device__ __forceinline__ float rdlanef(float v, int srcLane) {
    return __uint_as_float(
        (unsigned int)__builtin_amdgcn_readlane((int)__float_as_uint(v), srcLane));
}

// ---------------- Kernel 1: shared trajectory (fp32, 1 block) ----------------
__global__ __launch_bounds__(256) void traj_kernel(
    const float* __restrict__ cov0,  // (B,32,32) -> batch 0
    const float* __restrict__ Fm,    // (32,32)
    const float* __restrict__ Hm,    // (16,32)
    const float* __restrict__ Qm,    // (32,32)
    const float* __restrict__ Rm,    // (16,16)
    float* __restrict__ wsK,         // (T,512) + control int at T*512
    int T)
{
    __shared__ float P  [S_DIM*33];
    __shared__ float Fs [S_DIM*33];
    __shared__ float Qs [S_DIM*33];
    __shared__ float Tp [S_DIM*33];
    __shared__ float Hs [O_DIM*HS];
    __shared__ float HQ [O_DIM*HS];
    __shared__ float HPs[O_DIM*HS];
    __shared__ float KT [O_DIM*33];
    __shared__ float Sg [O_DIM*17];
    __shared__ float Rs [O_DIM*17];
    __shared__ int notId, notDiag;

    const int tid = threadIdx.x;

    for (int i = tid; i < S_DIM*S_DIM; i += 256) {
        int r = i >> 5, c = i & 31;
        P [r*33+c] = cov0[i];
        Fs[r*33+c] = Fm[i];
        Qs[r*33+c] = Qm[i];
    }
    for (int i = tid; i < O_DIM*S_DIM; i += 256) {
        int r = i >> 5, c = i & 31;
        Hs[r*HS+c] = Hm[i];
    }
    for (int i = tid; i < O_DIM*O_DIM; i += 256) {
        int r = i >> 4, c = i & 15;
        Rs[r*17+c] = Rm[i];
    }
    if (tid == 0) { notId = 0; notDiag = 0; }
    __syncthreads();

    {   // F == I and R-diagonal detection (block-uniform, deterministic)
        bool badI = false, badD = false;
        for (int i = tid; i < S_DIM*S_DIM; i += 256) {
            int r = i >> 5, c = i & 31;
            if (Fs[r*33+c] != ((r == c) ? 1.0f : 0.0f)) badI = true;
        }
        for (int i = tid; i < O_DIM*O_DIM; i += 256) {
            int r = i >> 4, c = i & 15;
            if (r != c && Rs[r*17+c] != 0.0f) badD = true;
        }
        if (badI) notId = 1;
        if (badD) notDiag = 1;
    }
    __syncthreads();
    const bool fId   = (notId == 0);
    const bool rDiag = (notDiag == 0);

    if (fId) {
        for (int i = tid; i < S_DIM*S_DIM; i += 256) {
            int r = i >> 5, c = i & 31;
            P[r*33+c] += Qs[r*33+c];
        }
        __syncthreads();
        // HP_0 = H*P_pred_0; HQ = H*Q
        int i0 = tid, i1 = tid + 256;
        int r0 = i0 >> 5, c0 = i0 & 31;
        int r1 = i1 >> 5, c1 = i1 & 31;
        float a0 = 0.f, a1 = 0.f, q0 = 0.f, q1 = 0.f;
        for (int k = 0; k < S_DIM; ++k) {
            a0 += Hs[r0*HS+k]*P [k*33+c0];
            a1 += Hs[r1*HS+k]*P [k*33+c1];
            q0 += Hs[r0*HS+k]*Qs[k*33+c0];
            q1 += Hs[r1*HS+k]*Qs[k*33+c1];
        }
        HPs[r0*HS+c0] = a0;  HPs[r1*HS+c1] = a1;
        HQ [r0*HS+c0] = q0;  HQ [r1*HS+c1] = q1;
        __syncthreads();

        // =================== single-wave main loop (wave 0) ===================
        if (tid >= 64) return;
        const int l = tid;
        const int c = l & 15;            // Phase-S column
        const int g = l >> 4;            // Phase-S row group (rows 4g..4g+3)
        const int myc = l;               // GJ column ownership
        const bool isS = (myc < O_DIM);
        const bool isK = (!isS && myc < 48);
        const int j  = myc - O_DIM;      // K row index (K lanes)
        const int hc = (myc - O_DIM) & 31;

        // hoisted constants
        float4 hrow[8];
        #pragma unroll
        for (int q = 0; q < 8; ++q) hrow[q] = *(const float4*)&Hs[c*HS + q*4];
        float rcol[4];
        #pragma unroll
        for (int i = 0; i < 4; ++i) rcol[i] = Rs[(4*g+i)*17 + c];
        float rdg[16], hq[16];
        if (isK) {
            #pragma unroll
            for (int r = 0; r < 16; ++r) { rdg[r] = Rs[r*17+r]; hq[r] = HQ[r*HS+j]; }
        }

        float prevK[16];
        #pragma unroll
        for (int r = 0; r < 16; ++r) prevK[r] = 0.f;
        int tc = T - 1;
        bool conv = false;

        for (int t = 0; t < T; ++t) {
            // ---- Phase S: S[4g+i][c] = HP[4g+i] . H[c] + R[4g+i][c] ----
            #pragma unroll
            for (int i = 0; i < 4; ++i) {
                const float4* hp = (const float4*)&HPs[(4*g+i)*HS];
                float a0 = rcol[i], a1 = 0.f, a2 = 0.f, a3 = 0.f;
                #pragma unroll
                for (int q = 0; q < 8; ++q) {
                    float4 u = hp[q], v = hrow[q];
                    a0 = fmaf(u.x, v.x, a0); a1 = fmaf(u.y, v.y, a1);
                    a2 = fmaf(u.z, v.z, a2); a3 = fmaf(u.w, v.w, a3);
                }
                Sg[(4*g+i)*17 + c] = (a0+a1)+(a2+a3);
            }
            __builtin_amdgcn_wave_barrier();

            // ---- register GJ on [S | HP] ----
            float a[16];
            #pragma unroll
            for (int r = 0; r < 16; ++r)
                a[r] = isS ? Sg[r*17+myc] : HPs[r*HS+hc];

            #pragma unroll
            for (int p = 0; p < 16; ++p) {
                float sp[16];
                #pragma unroll
                for (int r = 0; r < 16; ++r) sp[r] = rdlanef(a[r], p);
                float pinv = __builtin_amdgcn_rcpf(sp[p]);
                float sc = a[p] * pinv;
                #pragma unroll
                for (int r = 0; r < 16; ++r)
                    a[r] = (r == p) ? sc : fmaf(-sp[r], sc, a[r]);
            }

            // convergence check + K store + HP_next
            float d = 0.f;
            if (isK) {
                #pragma unroll
                for (int r = 0; r < 16; ++r) {
                    d = fmaxf(d, fabsf(a[r] - prevK[r]));
                    prevK[r] = a[r];
                }
            }
            unsigned long long anyBig = __ballot(isK && (d > 1e-5f));

            if (isK) {
                float4* dst = (float4*)(wsK + (long)t*K_STRIDE + j*O_DIM);
                dst[0] = make_float4(a[0],  a[1],  a[2],  a[3]);
                dst[1] = make_float4(a[4],  a[5],  a[6],  a[7]);
                dst[2] = make_float4(a[8],  a[9],  a[10], a[11]);
                dst[3] = make_float4(a[12], a[13], a[14], a[15]);
                if (rDiag) {
                    #pragma unroll
                    for (int r = 0; r < 16; ++r)
                        HPs[r*HS+j] = fmaf(rdg[r], a[r], hq[r]);
                } else {
                    #pragma unroll
                    for (int r = 0; r < 16; ++r) {
                        float rg = 0.f;
                        for (int k = 0; k < 16; ++k) rg += Rs[r*17+k]*a[k];
                        HPs[r*HS+j] = rg + hq[r];
                    }
                }
            }
            __builtin_amdgcn_wave_barrier();

            if (t >= 1 && anyBig == 0ull) { tc = t; conv = true; break; }
        }

        // tail fill from registers (no global read-back)
        if (conv && isK) {
            for (int t = tc + 1; t < T; ++t) {
                float4* dst = (float4*)(wsK + (long)t*K_STRIDE + j*O_DIM);
                dst[0] = make_float4(prevK[0],  prevK[1],  prevK[2],  prevK[3]);
                dst[1] = make_float4(prevK[4],  prevK[5],  prevK[6],  prevK[7]);
                dst[2] = make_float4(prevK[8],  prevK[9],  prevK[10], prevK[11]);
                dst[3] = make_float4(prevK[12], prevK[13], prevK[14], prevK[15]);
            }
        }
        if (l == 0)
            *(int*)(wsK + (long)T * K_STRIDE) = conv ? tc : T;
        return;
    }

    // =================== general-F fallback (multi-wave, rare) ===================
    for (int t = 0; t < T; ++t) {
        // predict: P = F P F^T + Q, then HP = H P
        for (int i = tid; i < S_DIM*S_DIM; i += 256) {
            int r = i >> 5, c = i & 31;
            float a = 0.f;
            for (int k = 0; k < S_DIM; ++k) a += Fs[r*33+k]*P[k*33+c];
            Tp[r*33+c] = a;
        }
        __syncthreads();
        for (int i = tid; i < S_DIM*S_DIM; i += 256) {
            int r = i >> 5, c = i & 31;
            float a = Qs[r*33+c];
            for (int k = 0; k < S_DIM; ++k) a += Tp[r*33+k]*Fs[c*33+k];
            P[r*33+c] = a;
        }
        __syncthreads();
        {
            int i0 = tid, i1 = tid + 256;
            int r0 = i0 >> 5, c0 = i0 & 31;
            int r1 = i1 >> 5, c1 = i1 & 31;
            float a0 = 0.f, a1 = 0.f;
            for (int k = 0; k < S_DIM; ++k) {
                a0 += Hs[r0*HS+k]*P[k*33+c0];
                a1 += Hs[r1*HS+k]*P[k*33+c1];
            }
            HPs[r0*HS+c0] = a0;
            HPs[r1*HS+c1] = a1;
        }
        __syncthreads();

        // S = HP H^T + R
        {
            int r = tid >> 4, c = tid & 15;
            float a = Rs[r*17+c];
            const float4* hp = (const float4*)&HPs[r*HS];
            const float4* hh = (const float4*)&Hs [c*HS];
            #pragma unroll
            for (int k = 0; k < 8; ++k) {
                float4 u = hp[k], v = hh[k];
                a += u.x*v.x + u.y*v.y + u.z*v.z + u.w*v.w;
            }
            Sg[r*17+c] = a;
        }
        __syncthreads();

        if (tid < 64) {
            const int myc = tid;
            const bool isS = (myc < O_DIM);
            const int hc = (myc - O_DIM) & 31;
            float a[16];
            #pragma unroll
            for (int r = 0; r < O_DIM; ++r)
                a[r] = isS ? Sg[r*17+myc] : HPs[r*HS+hc];
            #pragma unroll
            for (int p = 0; p < O_DIM; ++p) {
                float sp[16];
                #pragma unroll
                for (int r = 0; r < O_DIM; ++r) sp[r] = rdlanef(a[r], p);
                float pinv = __builtin_amdgcn_rcpf(sp[p]);
                float sc = a[p] * pinv;
                #pragma unroll
                for (int r = 0; r < O_DIM; ++r)
                    a[r] = (r == p) ? sc : fmaf(-sp[r], sc, a[r]);
            }
            if (!isS && myc < 48) {
                const int j = myc - O_DIM;
                float4* dst = (float4*)(wsK + (long)t*K_STRIDE + j*O_DIM);
                dst[0] = make_float4(a[0],  a[1],  a[2],  a[3]);
                dst[1] = make_float4(a[4],  a[5],  a[6],  a[7]);
                dst[2] = make_float4(a[8],  a[9],  a[10], a[11]);
                dst[3] = make_float4(a[12], a[13], a[14], a[15]);
                #pragma unroll
                for (int o = 0; o < O_DIM; ++o) KT[o*33+j] = a[o];
            }
        }
        __syncthreads();

        // P = P_pred - K*HP
        for (int i = tid; i < S_DIM*S_DIM; i += 256) {
            int r = i >> 5, c = i & 31;
            float acc = 0.f;
            for (int o = 0; o < O_DIM; ++o) acc += KT[o*33+r]*HPs[o*HS+c];
            P[r*33+c] -= acc;
        }
        __syncthreads();
    }
    if (tid == 0)
        *(int*)(wsK + (long)T * K_STRIDE) = T;   // no constant-K tail
}

// ---------------- Kernel 2: batch recursion, ONE WAVE PER BATCH, LDS-free ----
// x, innov, z are wave-uniform per lane index -> broadcasts via v_readlane.
__global__ __launch_bounds__(64) void batch_kernel(
    const float* __restrict__ state0,  // (B,32)
    const float* __restrict__ meas,    // (B,T,16)
    const float* __restrict__ wsK,     // (T,512) + control int
    const float* __restrict__ Fm,      // (32,32)
    const float* __restrict__ Hm,      // (16,32)
    float* __restrict__ out,           // (B,T,32)
    int T)
{
    const int l = threadIdx.x;       // 0..63
    const int s = l & 31;            // state index (row of K/M/F)
    const int o = l & 15;            // obs index (row of H, z element)
    const long b = blockIdx.x;

    const int tailStart = *(const int*)(wsK + (long)T * K_STRIDE);

    // H row o -> registers (32 floats)
    float hR[32];
    {
        const float4* Hv = (const float4*)(Hm + o*S_DIM);
        #pragma unroll
        for (int q = 0; q < 8; ++q) {
            float4 v = Hv[q];
            hR[q*4+0]=v.x; hR[q*4+1]=v.y; hR[q*4+2]=v.z; hR[q*4+3]=v.w;
        }
    }

    // F == I detection (single wave -> ballot, no LDS)
    bool bad = false;
    for (int i = l; i < S_DIM*S_DIM; i += 64) {
        int r = i >> 5, c = i & 31;
        if (Fm[i] != ((r == c) ? 1.0f : 0.0f)) bad = true;
    }
    const bool fId = (__ballot(bad) == 0ull);

    // F row s (general path only)
    float fR[32];
    if (!fId) {
        const float4* Fv = (const float4*)(Fm + s*S_DIM);
        #pragma unroll
        for (int q = 0; q < 8; ++q) {
            float4 v = Fv[q];
            fR[q*4+0]=v.x; fR[q*4+1]=v.y; fR[q*4+2]=v.z; fR[q*4+3]=v.w;
        }
    }

    float x = state0[b*S_DIM + s];

    // ===================== Phase A: K-form, depth-2 prefetch =====================
    float4 ka[4], kb[4]; float za, zb;
    {
        const float4* Kv = (const float4*)(wsK + 0*K_STRIDE + s*O_DIM);
        #pragma unroll
        for (int q = 0; q < 4; ++q) ka[q] = Kv[q];
        za = meas[(b*T + 0)*O_DIM + o];
        const int t1 = (1 < T) ? 1 : 0;
        const float4* Kv1 = (const float4*)(wsK + (long)t1*K_STRIDE + s*O_DIM);
        #pragma unroll
        for (int q = 0; q < 4; ++q) kb[q] = Kv1[q];
        zb = meas[(b*T + t1)*O_DIM + o];
    }

    int t = 0;
    for (; t < tailStart; ++t) {
        float4 kc[4]; float zc;
        {
            const int tn = (t + 2 < T) ? (t + 2) : (T - 1);
            const float4* Kv = (const float4*)(wsK + (long)tn*K_STRIDE + s*O_DIM);
            #pragma unroll
            for (int q = 0; q < 4; ++q) kc[q] = Kv[q];
            zc = meas[(b*T + tn)*O_DIM + o];
        }

        if (!fId) {   // xp = F x via readlane broadcasts
            float p0 = 0.f, p1 = 0.f, p2 = 0.f, p3 = 0.f;
            #pragma unroll
            for (int jj = 0; jj < 32; jj += 4) {
                p0 = fmaf(fR[jj+0], rdlanef(x, jj+0), p0);
                p1 = fmaf(fR[jj+1], rdlanef(x, jj+1), p1);
                p2 = fmaf(fR[jj+2], rdlanef(x, jj+2), p2);
                p3 = fmaf(fR[jj+3], rdlanef(x, jj+3), p3);
            }
            x = (p0 + p1) + (p2 + p3);
        }

        // y_o = H[o] . x  (full dot, replicated 4x across lanes with same o)
        float y0 = 0.f, y1 = 0.f, y2 = 0.f, y3 = 0.f;
        #pragma unroll
        for (int jj = 0; jj < 32; jj += 4) {
            y0 = fmaf(hR[jj+0], rdlanef(x, jj+0), y0);
            y1 = fmaf(hR[jj+1], rdlanef(x, jj+1), y1);
            y2 = fmaf(hR[jj+2], rdlanef(x, jj+2), y2);
            y3 = fmaf(hR[jj+3], rdlanef(x, jj+3), y3);
        }
        float innov = za - ((y0 + y1) + (y2 + y3));
        // innov_o now valid in lane o (and replicas)

        float kr[16] = {ka[0].x,ka[0].y,ka[0].z,ka[0].w,
                        ka[1].x,ka[1].y,ka[1].z,ka[1].w,
                        ka[2].x,ka[2].y,ka[2].z,ka[2].w,
                        ka[3].x,ka[3].y,ka[3].z,ka[3].w};
        float a0 = 0.f, a1 = 0.f, a2 = 0.f, a3 = 0.f;
        #pragma unroll
        for (int oo = 0; oo < 16; oo += 4) {
            a0 = fmaf(kr[oo+0], rdlanef(innov, oo+0), a0);
            a1 = fmaf(kr[oo+1], rdlanef(innov, oo+1), a1);
            a2 = fmaf(kr[oo+2], rdlanef(innov, oo+2), a2);
            a3 = fmaf(kr[oo+3], rdlanef(innov, oo+3), a3);
        }
        float xnew = x + ((a0 + a1) + (a2 + a3));

        if (l < 32) out[(b*T + t)*S_DIM + s] = xnew;
        x = xnew;

        #pragma unroll
        for (int q = 0; q < 4; ++q) { ka[q] = kb[q]; kb[q] = kc[q]; }
        za = zb; zb = zc;
    }

    if (t >= T) return;

    // ===================== Phase B: constant-K tail =====================
    // kc16 = K_c row s; m = row s of M_c = I - K_c H (H[oo][j] via readlane of hR)
    float kc16[16];
    {
        const float4* Kr = (const float4*)(wsK + (long)tailStart*K_STRIDE + s*O_DIM);
        float4 k0 = Kr[0], k1 = Kr[1], k2 = Kr[2], k3 = Kr[3];
        kc16[0]=k0.x; kc16[1]=k0.y; kc16[2]=k0.z; kc16[3]=k0.w;
        kc16[4]=k1.x; kc16[5]=k1.y; kc16[6]=k1.z; kc16[7]=k1.w;
        kc16[8]=k2.x; kc16[9]=k2.y; kc16[10]=k2.z; kc16[11]=k2.w;
        kc16[12]=k3.x; kc16[13]=k3.y; kc16[14]=k3.z; kc16[15]=k3.w;
    }
    float m[32];
    #pragma unroll
    for (int jj = 0; jj < 32; ++jj) m[jj] = (s == jj) ? 1.0f : 0.0f;
    #pragma unroll
    for (int oo = 0; oo < 16; ++oo) {
        float kv = kc16[oo];
        #pragma unroll
        for (int jj = 0; jj < 32; ++jj)
            m[jj] = fmaf(-kv, rdlanef(hR[jj], oo), m[jj]);
    }

    // z depth-2 prefetch
    {
        za = meas[(b*T + t)*O_DIM + o];
        const int t1 = (t + 1 < T) ? (t + 1) : t;
        zb = meas[(b*T + t1)*O_DIM + o];
    }

    for (; t < T; ++t) {
        float zc;
        {
            const int tn = (t + 2 < T) ? (t + 2) : (T - 1);
            zc = meas[(b*T + tn)*O_DIM + o];
        }

        float p0 = 0.f, p1 = 0.f, p2 = 0.f, p3 = 0.f;
        #pragma unroll
        for (int jj = 0; jj < 32; jj += 4) {
            p0 = fmaf(m[jj+0], rdlanef(x, jj+0), p0);
            p1 = fmaf(m[jj+1], rdlanef(x, jj+1), p1);
            p2 = fmaf(m[jj+2], rdlanef(x, jj+2), p2);
            p3 = fmaf(m[jj+3], rdlanef(x, jj+3), p3);
        }
        float a0 = 0.f, a1 = 0.f, a2 = 0.f, a3 = 0.f;
        #pragma unroll
        for (int oo = 0; oo < 16; oo += 4) {
            a0 = fmaf(kc16[oo+0], rdlanef(za, oo+0), a0);
            a1 = fmaf(kc16[oo+1], rdlanef(za, oo+1), a1);
            a2 = fmaf(kc16[oo+2], rdlanef(za, oo+2), a2);
            a3 = fmaf(kc16[oo+3], rdlanef(za, oo+3), a3);
        }
        float xnew = ((p0 + p1) + (p2 + p3)) + ((a0 + a1) + (a2 + a3));

        if (l < 32) out[(b*T + t)*S_DIM + s] = xnew;
        x = xnew;
        za = zb; zb = zc;
    }
}

extern "C" void kernel_launch(void* const* d_in, const int* in_sizes, int n_in,
                              void* d_out, int out_size, void* d_ws, size_t ws_size,
                              hipStream_t stream) {
    const float* state0 = (const float*)d_in[0];
    const float* cov0   = (const float*)d_in[1];
    const float* meas   = (const float*)d_in[2];
    const float* Fm     = (const float*)d_in[3];
    const float* Hm     = (const float*)d_in[4];
    const float* Qm     = (const float*)d_in[5];
    const float* Rm     = (const float*)d_in[6];
    float* out  = (float*)d_out;
    float* wsK  = (float*)d_ws;

    const int B = in_sizes[0] / S_DIM;               // 2048
    const int T = in_sizes[2] / (B * O_DIM);         // 64

    traj_kernel<<<dim3(1), dim3(256), 0, stream>>>(cov0, Fm, Hm, Qm, Rm, wsK, T);
    batch_kernel<<<dim3(B), dim3(64), 0, stream>>>(state0, meas, wsK, Fm, Hm, out, T);
}